// Round 10
// baseline (148.106 us; speedup 1.0000x reference)
//
#include <hip/hip_runtime.h>

#define KK 4096
#define NN 11008
#define NGRP 32
#define KW 2048             // int32 words per qweight row
#define WS_RS_OFF 131072    // ws: [0,128K) A_perm bf16; [128K,+2K) rowsum
#define WS_SZ_OFF 139264    // [136K, +1.41M) SZ[n][g] = s*(128+z)

using short8  = __attribute__((ext_vector_type(8))) short;
using float4v = __attribute__((ext_vector_type(4))) float;

static __device__ __forceinline__ unsigned int pack_bf16(float lo, float hi) {
    unsigned int ul = __builtin_bit_cast(unsigned int, lo);
    unsigned int uh = __builtin_bit_cast(unsigned int, hi);
    ul = (ul + 0x7FFFu + ((ul >> 16) & 1u)) >> 16;
    uh = (uh + 0x7FFFu + ((uh >> 16) & 1u)) & 0xFFFF0000u;
    return ul | uh;
}
static __device__ __forceinline__ float bf16val(float f) {
    unsigned int u = __builtin_bit_cast(unsigned int, f);
    u = (u + 0x7FFFu + ((u >> 16) & 1u)) & 0xFFFF0000u;
    return __builtin_bit_cast(float, u);
}

// prep: b<32  -> A_perm fragment-linear bf16 A: chunk c=k/32 at shorts
//                [c*512,+512); lane l holds A[l&15][c*32+(l>>4)*8..+8]
//       32-63 -> per-(m,group) row sums of bf16(A)
//       >=64  -> SZ[n][g] = scales*(128+zeros)
__global__ __launch_bounds__(256) void prep_kernel(
    const float* __restrict__ A, const float* __restrict__ scales,
    const float* __restrict__ zeros, unsigned short* __restrict__ wsA,
    float* __restrict__ rowsum, float* __restrict__ SZ)
{
    const int b = blockIdx.x, t = threadIdx.x;
    if (b < 32) {
        const int tid = b * 256 + t;
        const int c = tid >> 6, l = tid & 63;
        const float* src = A + (size_t)(l & 15) * KK + c * 32 + (l >> 4) * 8;
        float4v x0 = *(const float4v*)src;
        float4v x1 = *(const float4v*)(src + 4);
        union { short8 s8; unsigned int u[4]; } p;
        p.u[0] = pack_bf16(x0[0], x0[1]);
        p.u[1] = pack_bf16(x0[2], x0[3]);
        p.u[2] = pack_bf16(x1[0], x1[1]);
        p.u[3] = pack_bf16(x1[2], x1[3]);
        *(short8*)(wsA + (size_t)tid * 8) = p.s8;
    } else if (b < 64) {
        const int sid = (b - 32) * 16 + (t >> 4);   // m*32+g
        const int m = sid >> 5, g = sid & 31, j = t & 15;
        const float* p = A + (size_t)m * KK + g * 128 + j * 8;
        float4v x0 = *(const float4v*)p;
        float4v x1 = *(const float4v*)(p + 4);
        float sum = bf16val(x0[0]) + bf16val(x0[1]) + bf16val(x0[2]) + bf16val(x0[3])
                  + bf16val(x1[0]) + bf16val(x1[1]) + bf16val(x1[2]) + bf16val(x1[3]);
        sum += __shfl_xor(sum, 1, 16);
        sum += __shfl_xor(sum, 2, 16);
        sum += __shfl_xor(sum, 4, 16);
        sum += __shfl_xor(sum, 8, 16);
        if (j == 0) rowsum[sid] = sum;
    } else {
        const int e0 = (b - 64) * 1024 + t * 4;
        float4v s4 = *(const float4v*)(scales + e0);
        float4v z4 = *(const float4v*)(zeros + e0);
        float4v r;
        #pragma unroll
        for (int j = 0; j < 4; ++j) r[j] = s4[j] * (128.0f + z4[j]);
        *(float4v*)(SZ + e0) = r;
    }
}

// init_out: out[m][n] = bias[n] - sum_g SZ[n][g]*rowsum[m][g]
__global__ __launch_bounds__(256) void init_out_kernel(
    const float* __restrict__ bias, const float* __restrict__ SZ,
    const float* __restrict__ rowsum, float* __restrict__ out)
{
    __shared__ float rs[16][32];
    const int t = threadIdx.x;
    rs[t >> 5][t & 31]       = rowsum[t];
    rs[(t >> 5) + 8][t & 31] = rowsum[t + 256];
    __syncthreads();
    const int n0 = blockIdx.x * 16;
    const int m = t >> 4, nn = t & 15, ng = n0 + nn;
    const float* szr = SZ + (size_t)ng * NGRP;
    float corr = 0.f;
    #pragma unroll
    for (int g = 0; g < 32; ++g)
        corr = __builtin_fmaf(szr[g], rs[m][g], corr);
    out[(size_t)m * NN + ng] = bias[ng] - corr;
}

// Hot kernel: 1376 blocks = 688 n-tiles x 2 k-halves, 4 waves. Stage 16 rows
// x 4KB (this k-half) into 64KB LDS with 1KB-contiguous wave loads (R9 p-m:
// the 16-row x 64B fragment scatter caps DRAM at ~2 TB/s; this restores the
// m13 copy pattern). ONE barrier per 64KB (R7's per-512B barrier drain was the
// killer). Compute from LDS; 16-way column-read conflicts (~1k cyc/wave) hide
// under the ~5us/block staging time.
__global__ __launch_bounds__(256, 2) void qgemm_kernel(
    const int*            __restrict__ qweight,  // (11008, 2048) words
    const float*          __restrict__ scales,   // (11008, 32)
    const unsigned short* __restrict__ aperm,    // fragment-linear bf16 A
    float*                __restrict__ out)      // (16, 11008) fp32
{
    __shared__ __align__(16) char tile[65536];   // 16 rows x 4096 B

    const int nt = blockIdx.x >> 1, kh = blockIdx.x & 1;
    const int n0 = nt * 16;
    const int wid = threadIdx.x >> 6, lane = threadIdx.x & 63;
    const int nl = lane & 15, quad = lane >> 4;

    // ---- stage: wave wid loads rows [wid*4, wid*4+4), 4 x 1KB per row ----
    const char* gbase = (const char*)qweight + (size_t)n0 * 8192 + kh * 4096;
    int4 stg[16];
    #pragma unroll
    for (int i = 0; i < 16; ++i) {
        const int r = wid * 4 + (i >> 2), c = i & 3;
        stg[i] = *(const int4*)(gbase + (size_t)r * 8192 + c * 1024 + (lane << 4));
    }
    #pragma unroll
    for (int i = 0; i < 16; ++i) {
        const int r = wid * 4 + (i >> 2), c = i & 3;
        *(int4*)(tile + r * 4096 + c * 1024 + (lane << 4)) = stg[i];
    }
    __syncthreads();

    // ---- compute: wave wid covers chunks [wid*16, wid*16+16) = 4 groups ----
    const float* srow = scales + (size_t)(n0 + nl) * NGRP + kh * 16 + wid * 4;
    float4v acc = {0.f, 0.f, 0.f, 0.f};
    #pragma unroll
    for (int gl = 0; gl < 4; ++gl) {
        const int ch0 = wid * 16 + gl * 4;       // chunk within half (0..63)
        float4v accg = {0.f, 0.f, 0.f, 0.f};
        #pragma unroll
        for (int t = 0; t < 4; ++t) {
            const unsigned short* ap =
                aperm + (size_t)(kh * 64 + ch0 + t) * 512 + lane * 8;
            short8 a = *(const short8*)ap;
            int4 wv = *(const int4*)(tile + nl * 4096 + (ch0 + t) * 64 + quad * 16);
            const unsigned int x0 = (unsigned int)wv.x, x1 = (unsigned int)wv.y;
            const unsigned int x2 = (unsigned int)wv.z, x3 = (unsigned int)wv.w;
            union { short8 s8; unsigned int u[4]; } bf;   // exact bf16(128+q)
            bf.u[0] = (x0 & 0xFu) | ((x0 << 12) & 0x000F0000u) | 0x43004300u;
            bf.u[1] = (x1 & 0xFu) | ((x1 << 12) & 0x000F0000u) | 0x43004300u;
            bf.u[2] = (x2 & 0xFu) | ((x2 << 12) & 0x000F0000u) | 0x43004300u;
            bf.u[3] = (x3 & 0xFu) | ((x3 << 12) & 0x000F0000u) | 0x43004300u;
            accg = __builtin_amdgcn_mfma_f32_16x16x32_bf16(a, bf.s8, accg, 0, 0, 0);
        }
        const float sg = srow[gl];
        #pragma unroll
        for (int r = 0; r < 4; ++r)
            acc[r] = __builtin_fmaf(sg, accg[r], acc[r]);
    }

    // ---- reduce: reuse tile as red[4][16][16] after all reads complete ----
    __syncthreads();
    float* red = (float*)tile;
    #pragma unroll
    for (int r = 0; r < 4; ++r)
        red[wid * 256 + (quad * 4 + r) * 16 + nl] = acc[r];  // C/D: m=quad*4+r [m89]
    __syncthreads();

    const int t = threadIdx.x;
    const int m = t >> 4, nn = t & 15;
    float val = red[m * 16 + nn] + red[256 + m * 16 + nn]
              + red[512 + m * 16 + nn] + red[768 + m * 16 + nn];
    atomicAdd(&out[(size_t)m * NN + n0 + nn], val);  // 2 adds/output (kh=0,1)
}

extern "C" void kernel_launch(void* const* d_in, const int* in_sizes, int n_in,
                              void* d_out, int out_size, void* d_ws, size_t ws_size,
                              hipStream_t stream) {
    const float* A       = (const float*)d_in[0];
    const int*   qweight = (const int*)d_in[1];
    const float* scales  = (const float*)d_in[2];
    const float* zeros   = (const float*)d_in[3];
    const float* bias    = (const float*)d_in[4];
    float*       out     = (float*)d_out;

    unsigned short* wsA = (unsigned short*)d_ws;
    float* rowsum       = (float*)((char*)d_ws + WS_RS_OFF);
    float* SZ           = (float*)((char*)d_ws + WS_SZ_OFF);

    prep_kernel<<<dim3(408), dim3(256), 0, stream>>>(A, scales, zeros, wsA, rowsum, SZ);
    init_out_kernel<<<dim3(688), dim3(256), 0, stream>>>(bias, SZ, rowsum, out);
    qgemm_kernel<<<dim3(1376), dim3(256), 0, stream>>>(qweight, scales, wsA, out);
}